// Round 9
// baseline (470.678 us; speedup 1.0000x reference)
//
#include <hip/hip_runtime.h>
#include <hip/hip_bf16.h>

typedef __attribute__((ext_vector_type(8))) short short8;
typedef __attribute__((ext_vector_type(4))) float f32x4;

#define LOG2E 1.442695041f
#define LN2   0.69314718f

// sigmoid/silu on PRE-SCALED argument s = log2(e)*y:
//   sigma(y) = 1/(1+2^(-s)), silu-scaled = s*sigma = log2(e)*silu(y)
__device__ __forceinline__ float fsigmoid2(float s) {
  return __builtin_amdgcn_rcpf(1.0f + exp2f(-s));
}
__device__ __forceinline__ float fsilu2(float s) { return s * fsigmoid2(s); }
__device__ __forceinline__ unsigned short bf16b(float x) {
  union { float f; unsigned u; } c; c.f = x;
  unsigned r = c.u + 0x7FFFu + ((c.u >> 16) & 1u);
  return (unsigned short)(r >> 16);
}
__device__ __forceinline__ float b2f(unsigned short u) {
  union { unsigned v; float f; } c; c.v = ((unsigned)u) << 16; return c.f;
}
__device__ __forceinline__ short8 pack8(const float* v) {
  short8 r;
  #pragma unroll
  for (int m = 0; m < 4; ++m) {
    __hip_bfloat162 h = __float22bfloat162_rn(make_float2(v[2 * m], v[2 * m + 1]));
    short2 s2 = *reinterpret_cast<const short2*>(&h);
    r[2 * m] = s2.x; r[2 * m + 1] = s2.y;
  }
  return r;
}
template<int CTRL>
__device__ __forceinline__ float dpp_add(float x) {
  int xi = __builtin_bit_cast(int, x);
  int yi = __builtin_amdgcn_update_dpp(0, xi, CTRL, 0xF, 0xF, true);
  return x + __builtin_bit_cast(float, yi);
}
__device__ __forceinline__ float row16_sum(float x) {
  x = dpp_add<0x121>(x);
  x = dpp_add<0x122>(x);
  x = dpp_add<0x124>(x);
  x = dpp_add<0x128>(x);
  return x;
}

// ---- setup: bf16 B-fragments with log2(e)/ln2 scale-folding ----
//   EW1F x LOG2E            (pi/pj arrive pre-scaled: s1 = log2e*y1)
//   EW2F unchanged          (1.4427-scaled m1 in -> s2 = log2e*y2 out)
//   NW1F rows k<22 x LOG2E  (zn part; rows 22..85 carry 1.4427*m_i and the
//                            two folds cancel: *ln2*log2e = 1)
//   NW2F x LN2              (h1 stored as 1.4427*h1)
__global__ void setup_kernel(const float* __restrict__ eW1, const float* __restrict__ eW2,
                             const float* __restrict__ nW1, const float* __restrict__ nW2,
                             unsigned short* __restrict__ WS) {
  int t = blockIdx.x * 256 + threadIdx.x;
  float val = 0.f;
  if (t < 8192) {                       // EW1F
    int l = t >> 12, r = t & 4095;
    int nt = r >> 9, lane = (r >> 3) & 63, e = r & 7;
    int k = 8 * (lane >> 4) + e, n = 16 * nt + (lane & 15);
    if (k < 22) val = LOG2E * ((n < 64) ? eW1[l * 2816 + k * 64 + n]
                                        : eW1[l * 2816 + (22 + k) * 64 + (n - 64)]);
  } else if (t < 16384) {               // EW2F (unchanged values)
    int u = t - 8192;
    int l = u >> 12, r = u & 4095;
    int ks = r >> 11, nt = (r >> 9) & 3, lane = (r >> 3) & 63, e = r & 7;
    int k = 32 * ks + 8 * (lane >> 4) + e, n = 16 * nt + (lane & 15);
    val = eW2[l * 4096 + k * 64 + n];
  } else if (t < 28672) {               // NW1F
    int u = t - 16384;
    int l = u / 6144, r = u % 6144;
    int ks = r >> 11, nt = (r >> 9) & 3, lane = (r >> 3) & 63, e = r & 7;
    int k = 32 * ks + 8 * (lane >> 4) + e, n = 16 * nt + (lane & 15);
    if (k < 86) {
      val = nW1[l * 5504 + k * 64 + n];
      if (k < 22) val *= LOG2E;         // zn rows; macc rows: folds cancel
    }
  } else {                              // NW2F
    int u = t - 28672;
    int l = u >> 11, r = u & 2047;
    int ks = r >> 10, nt = (r >> 9) & 1, lane = (r >> 3) & 63, e = r & 7;
    int k = 32 * ks + 8 * (lane >> 4) + e, n = 16 * nt + (lane & 15);
    if (n < 22) val = LN2 * nW2[l * 1408 + k * 22 + n];
  }
  WS[t] = bf16b(val);
}

// ---- K1: z -> pi|pj projections (SPP bf16, log2e-scaled) + layernorm ----
__launch_bounds__(256, 4)
__global__ void proj_kernel(const float* __restrict__ X, const float* __restrict__ CTX,
                            const unsigned short* __restrict__ WS,
                            const float* __restrict__ EB1,
                            const float* __restrict__ LNG, const float* __restrict__ LNB,
                            float* __restrict__ Z, unsigned short* __restrict__ SPP,
                            unsigned short* __restrict__ CIN, int l)
{
  __shared__ float sz[29 * 36];
  const int b = blockIdx.x, tid = threadIdx.x;
  const int lane = tid & 63, w = tid >> 6;
  const int lr = lane & 15, lg = lane >> 4, kb = lg * 8;

  if (l == 0) {
    for (int t = tid; t < 29 * 36; t += 256) {
      int i = t / 36, c = t - i * 36;
      float v = 0.f;
      if (c < 6) v = X[b * 174 + i * 6 + c];
      else if (c < 22) v = CTX[b * 464 + i * 16 + (c - 6)];
      sz[t] = v;
      if (c < 32) Z[(b * 29 + i) * 32 + c] = v;
    }
  } else {
    for (int t = tid; t < 29 * 36; t += 256) {
      int i = t / 36, c = t - i * 36;
      sz[t] = (c < 32) ? Z[(b * 29 + i) * 32 + c] : 0.f;
    }
  }
  __syncthreads();

  {
    int rt = w >> 1;
    int rowc = min(16 * rt + lr, 28);
    float zr[8];
    *(float4*)&zr[0] = *(const float4*)&sz[rowc * 36 + kb];
    *(float4*)&zr[4] = *(const float4*)&sz[rowc * 36 + kb + 4];
    short8 af = pack8(zr);
    int ntb = 4 * (w & 1);
    const unsigned short* wp = WS + (l * 4096 + ntb * 512 + lane * 8);
    #pragma unroll
    for (int t = 0; t < 4; ++t) {
      short8 bfr = *(const short8*)(wp + t * 512);
      f32x4 zz = {0.f, 0.f, 0.f, 0.f};
      f32x4 acc = __builtin_amdgcn_mfma_f32_16x16x32_bf16(af, bfr, zz, 0, 0, 0);
      int n = 16 * (ntb + t) + lr;
      float bias = (ntb + t < 4) ? LOG2E * EB1[l * 64 + n] : 0.f;
      #pragma unroll
      for (int r = 0; r < 4; ++r) {
        int orow = 16 * rt + 4 * lg + r;
        if (orow < 29) SPP[(b * 29 + orow) * 128 + n] = bf16b(acc[r] + bias);
      }
    }
  }
  if (w == 3 && lane < 29) {
    const float* row = &sz[lane * 36];
    float s = 0.f, q = 0.f;
    #pragma unroll
    for (int c4 = 0; c4 < 6; ++c4) {
      float4 v = *(const float4*)(row + 4 * c4);
      s += v.x + v.y + v.z + v.w;
      q += v.x * v.x + v.y * v.y + v.z * v.z + v.w * v.w;
    }
    float mu = s * (1.f / 22.f);
    float var = q * (1.f / 22.f) - mu * mu;
    float rr = rsqrtf(var + 1e-5f);
    unsigned short* crow = CIN + (b * 29 + lane) * 96;
    #pragma unroll
    for (int d = 0; d < 22; ++d)
      crow[d] = bf16b((row[d] - mu) * rr * LNG[l * 22 + d] + LNB[l * 22 + d]);
    #pragma unroll
    for (int d = 86; d < 96; ++d) crow[d] = 0;
  }
}

// ---- K2: edge phase (R7 structure: one wave per (b, i-quarter), no LDS).
//      Scale-folded: no exp-arg muls, bias in accumulator init, gate fold.
__launch_bounds__(256, 2)
__global__ void edge_kernel(const unsigned short* __restrict__ WS,
                            const unsigned short* __restrict__ SPP,
                            const float* __restrict__ EB2, const float* __restrict__ GW,
                            const float* __restrict__ GB,
                            unsigned short* __restrict__ CIN, int l)
{
  const int tid = threadIdx.x;
  const int lane = tid & 63, w = tid >> 6;
  const int lr = lane & 15, lg = lane >> 4, kb = lg * 8;
  const int wid = blockIdx.x * 4 + w;          // 4096 blocks -> 16384 waves
  const int b = wid >> 2;
  const int slot = wid & 3;
  const int i0 = (slot * 29) >> 2;
  const int i1 = ((slot + 1) * 29) >> 2;

  const unsigned short* wp = WS + (8192 + l * 4096 + lane * 8);
  short8 w2f[2][4];
  #pragma unroll
  for (int s = 0; s < 2; ++s)
    #pragma unroll
    for (int t = 0; t < 4; ++t)
      w2f[s][t] = *(const short8*)(wp + s * 2048 + t * 512);
  float eb2c[4], gwc[4];
  #pragma unroll
  for (int t = 0; t < 4; ++t) {
    eb2c[t] = LOG2E * EB2[l * 64 + 16 * t + lr];   // bias, pre-scaled: acc init
    gwc[t]  = GW [l * 64 + 16 * t + lr];           // unchanged (folds cancel)
  }
  const float gbv = LOG2E * GB[l];

  // pj panel cached in registers; rows 29..31 clamped (gated off)
  float pjf[2][2][8];
  #pragma unroll
  for (int tb = 0; tb < 2; ++tb) {
    int ja = min(tb * 16 + lr, 28);
    const unsigned short* pjrow = SPP + (b * 29 + ja) * 128 + 64 + kb;
    short8 p0 = *(const short8*)(pjrow);
    short8 p1 = *(const short8*)(pjrow + 32);
    #pragma unroll
    for (int m = 0; m < 8; ++m) { pjf[tb][0][m] = b2f(p0[m]); pjf[tb][1][m] = b2f(p1[m]); }
  }

  const unsigned short* pibase = SPP + b * 29 * 128 + kb;
  unsigned short* cbase = CIN + (b * 29) * 96 + 22 + lane;

  #pragma unroll 1
  for (int i = i0; i < i1; ++i) {
    short8 pb0 = *(const short8*)(pibase + i * 128);
    short8 pb1 = *(const short8*)(pibase + i * 128 + 32);
    float pif[2][8];
    #pragma unroll
    for (int m = 0; m < 8; ++m) { pif[0][m] = b2f(pb0[m]); pif[1][m] = b2f(pb1[m]); }

    float macc[4] = {0.f, 0.f, 0.f, 0.f};
    #pragma unroll
    for (int tb = 0; tb < 2; ++tb) {
      float m1[8];
      #pragma unroll
      for (int m = 0; m < 8; ++m) m1[m] = fsilu2(pif[0][m] + pjf[tb][0][m]);
      short8 af0 = pack8(m1);
      #pragma unroll
      for (int m = 0; m < 8; ++m) m1[m] = fsilu2(pif[1][m] + pjf[tb][1][m]);
      short8 af1 = pack8(m1);

      f32x4 a0 = {eb2c[0], eb2c[0], eb2c[0], eb2c[0]};
      f32x4 a1 = {eb2c[1], eb2c[1], eb2c[1], eb2c[1]};
      f32x4 a2 = {eb2c[2], eb2c[2], eb2c[2], eb2c[2]};
      f32x4 a3 = {eb2c[3], eb2c[3], eb2c[3], eb2c[3]};
      a0 = __builtin_amdgcn_mfma_f32_16x16x32_bf16(af0, w2f[0][0], a0, 0, 0, 0);
      a1 = __builtin_amdgcn_mfma_f32_16x16x32_bf16(af0, w2f[0][1], a1, 0, 0, 0);
      a2 = __builtin_amdgcn_mfma_f32_16x16x32_bf16(af0, w2f[0][2], a2, 0, 0, 0);
      a3 = __builtin_amdgcn_mfma_f32_16x16x32_bf16(af0, w2f[0][3], a3, 0, 0, 0);
      a0 = __builtin_amdgcn_mfma_f32_16x16x32_bf16(af1, w2f[1][0], a0, 0, 0, 0);
      a1 = __builtin_amdgcn_mfma_f32_16x16x32_bf16(af1, w2f[1][1], a1, 0, 0, 0);
      a2 = __builtin_amdgcn_mfma_f32_16x16x32_bf16(af1, w2f[1][2], a2, 0, 0, 0);
      a3 = __builtin_amdgcn_mfma_f32_16x16x32_bf16(af1, w2f[1][3], a3, 0, 0, 0);

      float m2v[4][4];
      #pragma unroll
      for (int r = 0; r < 4; ++r) {
        m2v[0][r] = fsilu2(a0[r]);
        m2v[1][r] = fsilu2(a1[r]);
        m2v[2][r] = fsilu2(a2[r]);
        m2v[3][r] = fsilu2(a3[r]);
      }
      float g0 = m2v[0][0]*gwc[0] + m2v[1][0]*gwc[1] + m2v[2][0]*gwc[2] + m2v[3][0]*gwc[3];
      float g1 = m2v[0][1]*gwc[0] + m2v[1][1]*gwc[1] + m2v[2][1]*gwc[2] + m2v[3][1]*gwc[3];
      float g2 = m2v[0][2]*gwc[0] + m2v[1][2]*gwc[1] + m2v[2][2]*gwc[2] + m2v[3][2]*gwc[3];
      float g3 = m2v[0][3]*gwc[0] + m2v[1][3]*gwc[1] + m2v[2][3]*gwc[2] + m2v[3][3]*gwc[3];
      g0 = row16_sum(g0); g1 = row16_sum(g1); g2 = row16_sum(g2); g3 = row16_sum(g3);
      float gg[4] = {g0, g1, g2, g3};
      #pragma unroll
      for (int r = 0; r < 4; ++r) {
        int jrow = tb * 16 + 4 * lg + r;
        float gv = (jrow < 29) ? fsigmoid2(gg[r] + gbv) : 0.f;
        macc[0] += m2v[0][r] * gv;
        macc[1] += m2v[1][r] * gv;
        macc[2] += m2v[2][r] * gv;
        macc[3] += m2v[3][r] * gv;
      }
    }

    float red0 = macc[0], red1 = macc[1], red2 = macc[2], red3 = macc[3];
    red0 += __shfl_xor(red0, 16, 64); red0 += __shfl_xor(red0, 32, 64);
    red1 += __shfl_xor(red1, 16, 64); red1 += __shfl_xor(red1, 32, 64);
    red2 += __shfl_xor(red2, 16, 64); red2 += __shfl_xor(red2, 32, 64);
    red3 += __shfl_xor(red3, 16, 64); red3 += __shfl_xor(red3, 32, 64);
    float vs = (lg == 0) ? red0 : (lg == 1) ? red1 : (lg == 2) ? red2 : red3;
    cbase[i * 96] = bf16b(vs);   // stores log2e * m_i; undone by NW1F fold
  }
}

// ---- K3: node MLP + residual (+ head when l==1) ----
__launch_bounds__(256, 4)
__global__ void node_kernel(const unsigned short* __restrict__ WS,
                            const unsigned short* __restrict__ CIN,
                            const float* __restrict__ NB1, const float* __restrict__ NB2,
                            float* __restrict__ Z,
                            const float* __restrict__ HW1, const float* __restrict__ HB1,
                            const float* __restrict__ HW2, const float* __restrict__ HB2,
                            float* __restrict__ OUTP, int l)
{
  __shared__ float sz[29 * 32];
  __shared__ float sh1[29 * 68];
  __shared__ float szm[22], shh[64], sob[24];
  const int b = blockIdx.x, tid = threadIdx.x;
  const int lane = tid & 63, w = tid >> 6;
  const int lr = lane & 15, lg = lane >> 4, kb = lg * 8;

  for (int t = tid; t < 29 * 8; t += 256)
    ((float4*)sz)[t] = ((const float4*)(Z + b * 29 * 32))[t];
  __syncthreads();

  // h1s = fsilu2(log2e*y1) = log2e*h1 -> sh1 ; NW2F carries the ln2 undo
  {
    int rt = w >> 1;
    int ntb = 2 * (w & 1);
    int rowc = min(16 * rt + lr, 28);
    const unsigned short* arow = CIN + (b * 29 + rowc) * 96 + kb;
    const unsigned short* wp = WS + (16384 + l * 6144 + ntb * 512 + lane * 8);
    f32x4 acc[2] = {{0.f,0.f,0.f,0.f}, {0.f,0.f,0.f,0.f}};
    #pragma unroll
    for (int s = 0; s < 3; ++s) {
      short8 af = *(const short8*)(arow + 32 * s);
      #pragma unroll
      for (int t = 0; t < 2; ++t) {
        short8 bfr = *(const short8*)(wp + s * 2048 + t * 512);
        acc[t] = __builtin_amdgcn_mfma_f32_16x16x32_bf16(af, bfr, acc[t], 0, 0, 0);
      }
    }
    #pragma unroll
    for (int t = 0; t < 2; ++t) {
      int n = 16 * (ntb + t) + lr;
      float bias = LOG2E * NB1[l * 64 + n];
      #pragma unroll
      for (int r = 0; r < 4; ++r) {
        int orow = 16 * rt + 4 * lg + r;
        if (orow < 29) sh1[orow * 68 + n] = fsilu2(acc[t][r] + bias);
      }
    }
  }
  __syncthreads();

  {
    int rt = w & 1;
    int nt = w >> 1;
    int rowc = min(16 * rt + lr, 28);
    int d = 16 * nt + lr;
    const unsigned short* wp = WS + (28672 + l * 2048 + nt * 512 + lane * 8);
    f32x4 acc = {0.f, 0.f, 0.f, 0.f};
    #pragma unroll
    for (int s = 0; s < 2; ++s) {
      float ar[8];
      *(float4*)&ar[0] = *(const float4*)&sh1[rowc * 68 + kb + 32 * s];
      *(float4*)&ar[4] = *(const float4*)&sh1[rowc * 68 + kb + 32 * s + 4];
      short8 af = pack8(ar);
      short8 bfr = *(const short8*)(wp + s * 1024);
      acc = __builtin_amdgcn_mfma_f32_16x16x32_bf16(af, bfr, acc, 0, 0, 0);
    }
    float bias = (d < 22) ? NB2[l * 22 + d] : 0.f;
    #pragma unroll
    for (int r = 0; r < 4; ++r) {
      int orow = 16 * rt + 4 * lg + r;
      if (orow < 29 && d < 22) sz[orow * 32 + d] += acc[r] + bias;
    }
  }
  __syncthreads();

  if (l == 0) {
    for (int t = tid; t < 29 * 8; t += 256)
      ((float4*)(Z + b * 29 * 32))[t] = ((const float4*)sz)[t];
  } else {
    if (tid < 22) {
      float s = 0.f;
      #pragma unroll
      for (int i = 0; i < 29; ++i) s += sz[i * 32 + tid];
      szm[tid] = s * (1.f / 29.f);
    }
    __syncthreads();
    if (tid < 64) {
      float a = HB1[tid];
      #pragma unroll
      for (int d = 0; d < 22; ++d) a += szm[d] * HW1[d * 64 + tid];
      shh[tid] = fmaxf(a, 0.f);
    }
    __syncthreads();
    if (tid < 24) {
      float a = HB2[tid];
      #pragma unroll
      for (int m = 0; m < 64; ++m) a += shh[m] * HW2[m * 24 + tid];
      sob[tid] = a;
    }
    __syncthreads();
    for (int t = tid; t < 29 * 12; t += 256)
      OUTP[b * 348 + t] = (t < 24) ? sob[t] : 0.f;
  }
}

extern "C" void kernel_launch(void* const* d_in, const int* in_sizes, int n_in,
                              void* d_out, int out_size, void* d_ws, size_t ws_size,
                              hipStream_t stream) {
  const float* X   = (const float*)d_in[0];
  const float* CTX = (const float*)d_in[1];
  const float* EW1 = (const float*)d_in[2];
  const float* EB1 = (const float*)d_in[3];
  const float* EW2 = (const float*)d_in[4];
  const float* EB2 = (const float*)d_in[5];
  const float* GW  = (const float*)d_in[6];
  const float* GB  = (const float*)d_in[7];
  const float* LNG = (const float*)d_in[8];
  const float* LNB = (const float*)d_in[9];
  const float* NW1 = (const float*)d_in[10];
  const float* NB1 = (const float*)d_in[11];
  const float* NW2 = (const float*)d_in[12];
  const float* NB2 = (const float*)d_in[13];
  const float* HW1 = (const float*)d_in[14];
  const float* HB1 = (const float*)d_in[15];
  const float* HW2 = (const float*)d_in[16];
  const float* HB2 = (const float*)d_in[17];
  float* OUTP = (float*)d_out;

  // workspace: WS fragments 64KB | Z f32 15.2MB | SPP bf16 30.4MB | CIN bf16 22.8MB
  unsigned short* WS = (unsigned short*)d_ws;
  float* Z = (float*)((char*)d_ws + 65536);
  unsigned short* SPP = (unsigned short*)((char*)d_ws + 65536 + 15204352);
  unsigned short* CIN = (unsigned short*)((char*)d_ws + 65536 + 15204352 + 30408704);

  hipLaunchKernelGGL(setup_kernel, dim3(128), dim3(256), 0, stream,
                     EW1, EW2, NW1, NW2, WS);
  for (int l = 0; l < 2; ++l) {
    hipLaunchKernelGGL(proj_kernel, dim3(4096), dim3(256), 0, stream,
                       X, CTX, WS, EB1, LNG, LNB, Z, SPP, CIN, l);
    hipLaunchKernelGGL(edge_kernel, dim3(4096), dim3(256), 0, stream,
                       WS, SPP, EB2, GW, GB, CIN, l);
    hipLaunchKernelGGL(node_kernel, dim3(4096), dim3(256), 0, stream,
                       WS, CIN, NB1, NB2, Z, HW1, HB1, HW2, HB2, OUTP, l);
  }
}

// Round 10
// 335.812 us; speedup vs baseline: 1.4016x; 1.4016x over previous
//
#include <hip/hip_runtime.h>
#include <hip/hip_bf16.h>

typedef __attribute__((ext_vector_type(8))) short short8;
typedef __attribute__((ext_vector_type(4))) float f32x4;

#define LOG2E 1.442695041f
#define LN2   0.69314718f

// sigmoid/silu on PRE-SCALED argument s = log2(e)*y, raw v_exp_f32
// (R9 used libm exp2f -> OCML range-checked path, +5 VALU/call. Builtin = 1 trans op.)
__device__ __forceinline__ float fsigmoid2(float s) {
  return __builtin_amdgcn_rcpf(1.0f + __builtin_amdgcn_exp2f(-s));
}
__device__ __forceinline__ float fsilu2(float s) { return s * fsigmoid2(s); }
__device__ __forceinline__ unsigned short bf16b(float x) {
  union { float f; unsigned u; } c; c.f = x;
  unsigned r = c.u + 0x7FFFu + ((c.u >> 16) & 1u);
  return (unsigned short)(r >> 16);
}
__device__ __forceinline__ float b2f(unsigned short u) {
  union { unsigned v; float f; } c; c.v = ((unsigned)u) << 16; return c.f;
}
__device__ __forceinline__ short8 pack8(const float* v) {
  short8 r;
  #pragma unroll
  for (int m = 0; m < 4; ++m) {
    __hip_bfloat162 h = __float22bfloat162_rn(make_float2(v[2 * m], v[2 * m + 1]));
    short2 s2 = *reinterpret_cast<const short2*>(&h);
    r[2 * m] = s2.x; r[2 * m + 1] = s2.y;
  }
  return r;
}
template<int CTRL>
__device__ __forceinline__ float dpp_add(float x) {
  int xi = __builtin_bit_cast(int, x);
  int yi = __builtin_amdgcn_update_dpp(0, xi, CTRL, 0xF, 0xF, true);
  return x + __builtin_bit_cast(float, yi);
}
__device__ __forceinline__ float row16_sum(float x) {
  x = dpp_add<0x121>(x);
  x = dpp_add<0x122>(x);
  x = dpp_add<0x124>(x);
  x = dpp_add<0x128>(x);
  return x;
}

// ---- setup: bf16 B-fragments with log2(e)/ln2 scale-folding ----
//   EW1F x LOG2E            (pi/pj arrive pre-scaled: s1 = log2e*y1)
//   EW2F unchanged          (1.4427-scaled m1 in -> s2 = log2e*y2 out)
//   NW1F rows k<22 x LOG2E  (zn rows; macc rows carry 1.4427*m_i: folds cancel)
//   NW2F x LN2              (h1 stored as 1.4427*h1)
__global__ void setup_kernel(const float* __restrict__ eW1, const float* __restrict__ eW2,
                             const float* __restrict__ nW1, const float* __restrict__ nW2,
                             unsigned short* __restrict__ WS) {
  int t = blockIdx.x * 256 + threadIdx.x;
  float val = 0.f;
  if (t < 8192) {                       // EW1F
    int l = t >> 12, r = t & 4095;
    int nt = r >> 9, lane = (r >> 3) & 63, e = r & 7;
    int k = 8 * (lane >> 4) + e, n = 16 * nt + (lane & 15);
    if (k < 22) val = LOG2E * ((n < 64) ? eW1[l * 2816 + k * 64 + n]
                                        : eW1[l * 2816 + (22 + k) * 64 + (n - 64)]);
  } else if (t < 16384) {               // EW2F (unchanged values)
    int u = t - 8192;
    int l = u >> 12, r = u & 4095;
    int ks = r >> 11, nt = (r >> 9) & 3, lane = (r >> 3) & 63, e = r & 7;
    int k = 32 * ks + 8 * (lane >> 4) + e, n = 16 * nt + (lane & 15);
    val = eW2[l * 4096 + k * 64 + n];
  } else if (t < 28672) {               // NW1F
    int u = t - 16384;
    int l = u / 6144, r = u % 6144;
    int ks = r >> 11, nt = (r >> 9) & 3, lane = (r >> 3) & 63, e = r & 7;
    int k = 32 * ks + 8 * (lane >> 4) + e, n = 16 * nt + (lane & 15);
    if (k < 86) {
      val = nW1[l * 5504 + k * 64 + n];
      if (k < 22) val *= LOG2E;         // zn rows; macc rows: folds cancel
    }
  } else {                              // NW2F
    int u = t - 28672;
    int l = u >> 11, r = u & 2047;
    int ks = r >> 10, nt = (r >> 9) & 1, lane = (r >> 3) & 63, e = r & 7;
    int k = 32 * ks + 8 * (lane >> 4) + e, n = 16 * nt + (lane & 15);
    if (n < 22) val = LN2 * nW2[l * 1408 + k * 22 + n];
  }
  WS[t] = bf16b(val);
}

// ---- K1: z -> pi|pj projections (SPP bf16, log2e-scaled) + layernorm ----
__launch_bounds__(256, 4)
__global__ void proj_kernel(const float* __restrict__ X, const float* __restrict__ CTX,
                            const unsigned short* __restrict__ WS,
                            const float* __restrict__ EB1,
                            const float* __restrict__ LNG, const float* __restrict__ LNB,
                            float* __restrict__ Z, unsigned short* __restrict__ SPP,
                            unsigned short* __restrict__ CIN, int l)
{
  __shared__ float sz[29 * 36];
  const int b = blockIdx.x, tid = threadIdx.x;
  const int lane = tid & 63, w = tid >> 6;
  const int lr = lane & 15, lg = lane >> 4, kb = lg * 8;

  if (l == 0) {
    for (int t = tid; t < 29 * 36; t += 256) {
      int i = t / 36, c = t - i * 36;
      float v = 0.f;
      if (c < 6) v = X[b * 174 + i * 6 + c];
      else if (c < 22) v = CTX[b * 464 + i * 16 + (c - 6)];
      sz[t] = v;
      if (c < 32) Z[(b * 29 + i) * 32 + c] = v;
    }
  } else {
    for (int t = tid; t < 29 * 36; t += 256) {
      int i = t / 36, c = t - i * 36;
      sz[t] = (c < 32) ? Z[(b * 29 + i) * 32 + c] : 0.f;
    }
  }
  __syncthreads();

  {
    int rt = w >> 1;
    int rowc = min(16 * rt + lr, 28);
    float zr[8];
    *(float4*)&zr[0] = *(const float4*)&sz[rowc * 36 + kb];
    *(float4*)&zr[4] = *(const float4*)&sz[rowc * 36 + kb + 4];
    short8 af = pack8(zr);
    int ntb = 4 * (w & 1);
    const unsigned short* wp = WS + (l * 4096 + ntb * 512 + lane * 8);
    #pragma unroll
    for (int t = 0; t < 4; ++t) {
      short8 bfr = *(const short8*)(wp + t * 512);
      f32x4 zz = {0.f, 0.f, 0.f, 0.f};
      f32x4 acc = __builtin_amdgcn_mfma_f32_16x16x32_bf16(af, bfr, zz, 0, 0, 0);
      int n = 16 * (ntb + t) + lr;
      float bias = (ntb + t < 4) ? LOG2E * EB1[l * 64 + n] : 0.f;
      #pragma unroll
      for (int r = 0; r < 4; ++r) {
        int orow = 16 * rt + 4 * lg + r;
        if (orow < 29) SPP[(b * 29 + orow) * 128 + n] = bf16b(acc[r] + bias);
      }
    }
  }
  if (w == 3 && lane < 29) {
    const float* row = &sz[lane * 36];
    float s = 0.f, q = 0.f;
    #pragma unroll
    for (int c4 = 0; c4 < 6; ++c4) {
      float4 v = *(const float4*)(row + 4 * c4);
      s += v.x + v.y + v.z + v.w;
      q += v.x * v.x + v.y * v.y + v.z * v.z + v.w * v.w;
    }
    float mu = s * (1.f / 22.f);
    float var = q * (1.f / 22.f) - mu * mu;
    float rr = rsqrtf(var + 1e-5f);
    unsigned short* crow = CIN + (b * 29 + lane) * 96;
    #pragma unroll
    for (int d = 0; d < 22; ++d)
      crow[d] = bf16b((row[d] - mu) * rr * LNG[l * 22 + d] + LNB[l * 22 + d]);
    #pragma unroll
    for (int d = 86; d < 96; ++d) crow[d] = 0;
  }
}

// ---- K2: edge phase (R7 structure: one wave per (b, i-quarter), no LDS).
//      Scale-folded: no exp-arg muls, bias in accumulator init, gate fold.
__launch_bounds__(256, 2)
__global__ void edge_kernel(const unsigned short* __restrict__ WS,
                            const unsigned short* __restrict__ SPP,
                            const float* __restrict__ EB2, const float* __restrict__ GW,
                            const float* __restrict__ GB,
                            unsigned short* __restrict__ CIN, int l)
{
  const int tid = threadIdx.x;
  const int lane = tid & 63, w = tid >> 6;
  const int lr = lane & 15, lg = lane >> 4, kb = lg * 8;
  const int wid = blockIdx.x * 4 + w;          // 4096 blocks -> 16384 waves
  const int b = wid >> 2;
  const int slot = wid & 3;
  const int i0 = (slot * 29) >> 2;
  const int i1 = ((slot + 1) * 29) >> 2;

  const unsigned short* wp = WS + (8192 + l * 4096 + lane * 8);
  short8 w2f[2][4];
  #pragma unroll
  for (int s = 0; s < 2; ++s)
    #pragma unroll
    for (int t = 0; t < 4; ++t)
      w2f[s][t] = *(const short8*)(wp + s * 2048 + t * 512);
  float eb2c[4], gwc[4];
  #pragma unroll
  for (int t = 0; t < 4; ++t) {
    eb2c[t] = LOG2E * EB2[l * 64 + 16 * t + lr];   // bias, pre-scaled: acc init
    gwc[t]  = GW [l * 64 + 16 * t + lr];           // unchanged (folds cancel)
  }
  const float gbv = LOG2E * GB[l];

  // pj panel cached in registers; rows 29..31 clamped (gated off)
  float pjf[2][2][8];
  #pragma unroll
  for (int tb = 0; tb < 2; ++tb) {
    int ja = min(tb * 16 + lr, 28);
    const unsigned short* pjrow = SPP + (b * 29 + ja) * 128 + 64 + kb;
    short8 p0 = *(const short8*)(pjrow);
    short8 p1 = *(const short8*)(pjrow + 32);
    #pragma unroll
    for (int m = 0; m < 8; ++m) { pjf[tb][0][m] = b2f(p0[m]); pjf[tb][1][m] = b2f(p1[m]); }
  }

  const unsigned short* pibase = SPP + b * 29 * 128 + kb;
  unsigned short* cbase = CIN + (b * 29) * 96 + 22 + lane;

  #pragma unroll 1
  for (int i = i0; i < i1; ++i) {
    short8 pb0 = *(const short8*)(pibase + i * 128);
    short8 pb1 = *(const short8*)(pibase + i * 128 + 32);
    float pif[2][8];
    #pragma unroll
    for (int m = 0; m < 8; ++m) { pif[0][m] = b2f(pb0[m]); pif[1][m] = b2f(pb1[m]); }

    float macc[4] = {0.f, 0.f, 0.f, 0.f};
    #pragma unroll
    for (int tb = 0; tb < 2; ++tb) {
      float m1[8];
      #pragma unroll
      for (int m = 0; m < 8; ++m) m1[m] = fsilu2(pif[0][m] + pjf[tb][0][m]);
      short8 af0 = pack8(m1);
      #pragma unroll
      for (int m = 0; m < 8; ++m) m1[m] = fsilu2(pif[1][m] + pjf[tb][1][m]);
      short8 af1 = pack8(m1);

      f32x4 a0 = {eb2c[0], eb2c[0], eb2c[0], eb2c[0]};
      f32x4 a1 = {eb2c[1], eb2c[1], eb2c[1], eb2c[1]};
      f32x4 a2 = {eb2c[2], eb2c[2], eb2c[2], eb2c[2]};
      f32x4 a3 = {eb2c[3], eb2c[3], eb2c[3], eb2c[3]};
      a0 = __builtin_amdgcn_mfma_f32_16x16x32_bf16(af0, w2f[0][0], a0, 0, 0, 0);
      a1 = __builtin_amdgcn_mfma_f32_16x16x32_bf16(af0, w2f[0][1], a1, 0, 0, 0);
      a2 = __builtin_amdgcn_mfma_f32_16x16x32_bf16(af0, w2f[0][2], a2, 0, 0, 0);
      a3 = __builtin_amdgcn_mfma_f32_16x16x32_bf16(af0, w2f[0][3], a3, 0, 0, 0);
      a0 = __builtin_amdgcn_mfma_f32_16x16x32_bf16(af1, w2f[1][0], a0, 0, 0, 0);
      a1 = __builtin_amdgcn_mfma_f32_16x16x32_bf16(af1, w2f[1][1], a1, 0, 0, 0);
      a2 = __builtin_amdgcn_mfma_f32_16x16x32_bf16(af1, w2f[1][2], a2, 0, 0, 0);
      a3 = __builtin_amdgcn_mfma_f32_16x16x32_bf16(af1, w2f[1][3], a3, 0, 0, 0);

      float m2v[4][4];
      #pragma unroll
      for (int r = 0; r < 4; ++r) {
        m2v[0][r] = fsilu2(a0[r]);
        m2v[1][r] = fsilu2(a1[r]);
        m2v[2][r] = fsilu2(a2[r]);
        m2v[3][r] = fsilu2(a3[r]);
      }
      float g0 = m2v[0][0]*gwc[0] + m2v[1][0]*gwc[1] + m2v[2][0]*gwc[2] + m2v[3][0]*gwc[3];
      float g1 = m2v[0][1]*gwc[0] + m2v[1][1]*gwc[1] + m2v[2][1]*gwc[2] + m2v[3][1]*gwc[3];
      float g2 = m2v[0][2]*gwc[0] + m2v[1][2]*gwc[1] + m2v[2][2]*gwc[2] + m2v[3][2]*gwc[3];
      float g3 = m2v[0][3]*gwc[0] + m2v[1][3]*gwc[1] + m2v[2][3]*gwc[2] + m2v[3][3]*gwc[3];
      g0 = row16_sum(g0); g1 = row16_sum(g1); g2 = row16_sum(g2); g3 = row16_sum(g3);
      float gg[4] = {g0, g1, g2, g3};
      #pragma unroll
      for (int r = 0; r < 4; ++r) {
        int jrow = tb * 16 + 4 * lg + r;
        float gv = (jrow < 29) ? fsigmoid2(gg[r] + gbv) : 0.f;
        macc[0] += m2v[0][r] * gv;
        macc[1] += m2v[1][r] * gv;
        macc[2] += m2v[2][r] * gv;
        macc[3] += m2v[3][r] * gv;
      }
    }

    float red0 = macc[0], red1 = macc[1], red2 = macc[2], red3 = macc[3];
    red0 += __shfl_xor(red0, 16, 64); red0 += __shfl_xor(red0, 32, 64);
    red1 += __shfl_xor(red1, 16, 64); red1 += __shfl_xor(red1, 32, 64);
    red2 += __shfl_xor(red2, 16, 64); red2 += __shfl_xor(red2, 32, 64);
    red3 += __shfl_xor(red3, 16, 64); red3 += __shfl_xor(red3, 32, 64);
    float vs = (lg == 0) ? red0 : (lg == 1) ? red1 : (lg == 2) ? red2 : red3;
    cbase[i * 96] = bf16b(vs);   // stores log2e * m_i; undone by NW1F fold
  }
}

// ---- K3: node MLP + residual (+ head when l==1) ----
__launch_bounds__(256, 4)
__global__ void node_kernel(const unsigned short* __restrict__ WS,
                            const unsigned short* __restrict__ CIN,
                            const float* __restrict__ NB1, const float* __restrict__ NB2,
                            float* __restrict__ Z,
                            const float* __restrict__ HW1, const float* __restrict__ HB1,
                            const float* __restrict__ HW2, const float* __restrict__ HB2,
                            float* __restrict__ OUTP, int l)
{
  __shared__ float sz[29 * 32];
  __shared__ float sh1[29 * 68];
  __shared__ float szm[22], shh[64], sob[24];
  const int b = blockIdx.x, tid = threadIdx.x;
  const int lane = tid & 63, w = tid >> 6;
  const int lr = lane & 15, lg = lane >> 4, kb = lg * 8;

  for (int t = tid; t < 29 * 8; t += 256)
    ((float4*)sz)[t] = ((const float4*)(Z + b * 29 * 32))[t];
  __syncthreads();

  // h1s = fsilu2(log2e*y1) = log2e*h1 -> sh1 ; NW2F carries the ln2 undo
  {
    int rt = w >> 1;
    int ntb = 2 * (w & 1);
    int rowc = min(16 * rt + lr, 28);
    const unsigned short* arow = CIN + (b * 29 + rowc) * 96 + kb;
    const unsigned short* wp = WS + (16384 + l * 6144 + ntb * 512 + lane * 8);
    f32x4 acc[2] = {{0.f,0.f,0.f,0.f}, {0.f,0.f,0.f,0.f}};
    #pragma unroll
    for (int s = 0; s < 3; ++s) {
      short8 af = *(const short8*)(arow + 32 * s);
      #pragma unroll
      for (int t = 0; t < 2; ++t) {
        short8 bfr = *(const short8*)(wp + s * 2048 + t * 512);
        acc[t] = __builtin_amdgcn_mfma_f32_16x16x32_bf16(af, bfr, acc[t], 0, 0, 0);
      }
    }
    #pragma unroll
    for (int t = 0; t < 2; ++t) {
      int n = 16 * (ntb + t) + lr;
      float bias = LOG2E * NB1[l * 64 + n];
      #pragma unroll
      for (int r = 0; r < 4; ++r) {
        int orow = 16 * rt + 4 * lg + r;
        if (orow < 29) sh1[orow * 68 + n] = fsilu2(acc[t][r] + bias);
      }
    }
  }
  __syncthreads();

  {
    int rt = w & 1;
    int nt = w >> 1;
    int rowc = min(16 * rt + lr, 28);
    int d = 16 * nt + lr;
    const unsigned short* wp = WS + (28672 + l * 2048 + nt * 512 + lane * 8);
    f32x4 acc = {0.f, 0.f, 0.f, 0.f};
    #pragma unroll
    for (int s = 0; s < 2; ++s) {
      float ar[8];
      *(float4*)&ar[0] = *(const float4*)&sh1[rowc * 68 + kb + 32 * s];
      *(float4*)&ar[4] = *(const float4*)&sh1[rowc * 68 + kb + 32 * s + 4];
      short8 af = pack8(ar);
      short8 bfr = *(const short8*)(wp + s * 1024);
      acc = __builtin_amdgcn_mfma_f32_16x16x32_bf16(af, bfr, acc, 0, 0, 0);
    }
    float bias = (d < 22) ? NB2[l * 22 + d] : 0.f;
    #pragma unroll
    for (int r = 0; r < 4; ++r) {
      int orow = 16 * rt + 4 * lg + r;
      if (orow < 29 && d < 22) sz[orow * 32 + d] += acc[r] + bias;
    }
  }
  __syncthreads();

  if (l == 0) {
    for (int t = tid; t < 29 * 8; t += 256)
      ((float4*)(Z + b * 29 * 32))[t] = ((const float4*)sz)[t];
  } else {
    if (tid < 22) {
      float s = 0.f;
      #pragma unroll
      for (int i = 0; i < 29; ++i) s += sz[i * 32 + tid];
      szm[tid] = s * (1.f / 29.f);
    }
    __syncthreads();
    if (tid < 64) {
      float a = HB1[tid];
      #pragma unroll
      for (int d = 0; d < 22; ++d) a += szm[d] * HW1[d * 64 + tid];
      shh[tid] = fmaxf(a, 0.f);
    }
    __syncthreads();
    if (tid < 24) {
      float a = HB2[tid];
      #pragma unroll
      for (int m = 0; m < 64; ++m) a += shh[m] * HW2[m * 24 + tid];
      sob[tid] = a;
    }
    __syncthreads();
    for (int t = tid; t < 29 * 12; t += 256)
      OUTP[b * 348 + t] = (t < 24) ? sob[t] : 0.f;
  }
}

extern "C" void kernel_launch(void* const* d_in, const int* in_sizes, int n_in,
                              void* d_out, int out_size, void* d_ws, size_t ws_size,
                              hipStream_t stream) {
  const float* X   = (const float*)d_in[0];
  const float* CTX = (const float*)d_in[1];
  const float* EW1 = (const float*)d_in[2];
  const float* EB1 = (const float*)d_in[3];
  const float* EW2 = (const float*)d_in[4];
  const float* EB2 = (const float*)d_in[5];
  const float* GW  = (const float*)d_in[6];
  const float* GB  = (const float*)d_in[7];
  const float* LNG = (const float*)d_in[8];
  const float* LNB = (const float*)d_in[9];
  const float* NW1 = (const float*)d_in[10];
  const float* NB1 = (const float*)d_in[11];
  const float* NW2 = (const float*)d_in[12];
  const float* NB2 = (const float*)d_in[13];
  const float* HW1 = (const float*)d_in[14];
  const float* HB1 = (const float*)d_in[15];
  const float* HW2 = (const float*)d_in[16];
  const float* HB2 = (const float*)d_in[17];
  float* OUTP = (float*)d_out;

  // workspace: WS fragments 64KB | Z f32 15.2MB | SPP bf16 30.4MB | CIN bf16 22.8MB
  unsigned short* WS = (unsigned short*)d_ws;
  float* Z = (float*)((char*)d_ws + 65536);
  unsigned short* SPP = (unsigned short*)((char*)d_ws + 65536 + 15204352);
  unsigned short* CIN = (unsigned short*)((char*)d_ws + 65536 + 15204352 + 30408704);

  hipLaunchKernelGGL(setup_kernel, dim3(128), dim3(256), 0, stream,
                     EW1, EW2, NW1, NW2, WS);
  for (int l = 0; l < 2; ++l) {
    hipLaunchKernelGGL(proj_kernel, dim3(4096), dim3(256), 0, stream,
                       X, CTX, WS, EB1, LNG, LNB, Z, SPP, CIN, l);
    hipLaunchKernelGGL(edge_kernel, dim3(4096), dim3(256), 0, stream,
                       WS, SPP, EB2, GW, GB, CIN, l);
    hipLaunchKernelGGL(node_kernel, dim3(4096), dim3(256), 0, stream,
                       WS, CIN, NB1, NB2, Z, HW1, HB1, HW2, HB2, OUTP, l);
  }
}

// Round 12
// 335.657 us; speedup vs baseline: 1.4023x; 1.0005x over previous
//
#include <hip/hip_runtime.h>
#include <hip/hip_bf16.h>

typedef __attribute__((ext_vector_type(8))) short short8;
typedef __attribute__((ext_vector_type(4))) float f32x4;

#define LOG2E 1.442695041f
#define LN2   0.69314718f

// sigmoid on PRE-SCALED argument s = log2(e)*y, raw v_exp_f32 + v_rcp.
// (R11's magic-constant rcp replacement failed with an unwritten-output
// signature — reverted to the validated R10 form.)
__device__ __forceinline__ float fsigmoid2(float s) {
  return __builtin_amdgcn_rcpf(1.0f + __builtin_amdgcn_exp2f(-s));
}
__device__ __forceinline__ float fsilu2(float s) { return s * fsigmoid2(s); }
__device__ __forceinline__ unsigned short bf16b(float x) {
  union { float f; unsigned u; } c; c.f = x;
  unsigned r = c.u + 0x7FFFu + ((c.u >> 16) & 1u);
  return (unsigned short)(r >> 16);
}
__device__ __forceinline__ float b2f(unsigned short u) {
  union { unsigned v; float f; } c; c.v = ((unsigned)u) << 16; return c.f;
}
__device__ __forceinline__ short8 pack8(const float* v) {
  short8 r;
  #pragma unroll
  for (int m = 0; m < 4; ++m) {
    __hip_bfloat162 h = __float22bfloat162_rn(make_float2(v[2 * m], v[2 * m + 1]));
    short2 s2 = *reinterpret_cast<const short2*>(&h);
    r[2 * m] = s2.x; r[2 * m + 1] = s2.y;
  }
  return r;
}
template<int CTRL>
__device__ __forceinline__ float dpp_add(float x) {
  int xi = __builtin_bit_cast(int, x);
  int yi = __builtin_amdgcn_update_dpp(0, xi, CTRL, 0xF, 0xF, true);
  return x + __builtin_bit_cast(float, yi);
}
__device__ __forceinline__ float row16_sum(float x) {
  x = dpp_add<0x121>(x);
  x = dpp_add<0x122>(x);
  x = dpp_add<0x124>(x);
  x = dpp_add<0x128>(x);
  return x;
}

// ---- setup: bf16 B-fragments with log2(e)/ln2 scale-folding ----
__global__ void setup_kernel(const float* __restrict__ eW1, const float* __restrict__ eW2,
                             const float* __restrict__ nW1, const float* __restrict__ nW2,
                             unsigned short* __restrict__ WS) {
  int t = blockIdx.x * 256 + threadIdx.x;
  float val = 0.f;
  if (t < 8192) {                       // EW1F
    int l = t >> 12, r = t & 4095;
    int nt = r >> 9, lane = (r >> 3) & 63, e = r & 7;
    int k = 8 * (lane >> 4) + e, n = 16 * nt + (lane & 15);
    if (k < 22) val = LOG2E * ((n < 64) ? eW1[l * 2816 + k * 64 + n]
                                        : eW1[l * 2816 + (22 + k) * 64 + (n - 64)]);
  } else if (t < 16384) {               // EW2F (unchanged values)
    int u = t - 8192;
    int l = u >> 12, r = u & 4095;
    int ks = r >> 11, nt = (r >> 9) & 3, lane = (r >> 3) & 63, e = r & 7;
    int k = 32 * ks + 8 * (lane >> 4) + e, n = 16 * nt + (lane & 15);
    val = eW2[l * 4096 + k * 64 + n];
  } else if (t < 28672) {               // NW1F
    int u = t - 16384;
    int l = u / 6144, r = u % 6144;
    int ks = r >> 11, nt = (r >> 9) & 3, lane = (r >> 3) & 63, e = r & 7;
    int k = 32 * ks + 8 * (lane >> 4) + e, n = 16 * nt + (lane & 15);
    if (k < 86) {
      val = nW1[l * 5504 + k * 64 + n];
      if (k < 22) val *= LOG2E;         // zn rows; macc rows: folds cancel
    }
  } else {                              // NW2F
    int u = t - 28672;
    int l = u >> 11, r = u & 2047;
    int ks = r >> 10, nt = (r >> 9) & 1, lane = (r >> 3) & 63, e = r & 7;
    int k = 32 * ks + 8 * (lane >> 4) + e, n = 16 * nt + (lane & 15);
    if (n < 22) val = LN2 * nW2[l * 1408 + k * 22 + n];
  }
  WS[t] = bf16b(val);
}

// ---- K1: z -> pi|pj projections (SPP bf16, log2e-scaled) + layernorm ----
__launch_bounds__(256, 4)
__global__ void proj_kernel(const float* __restrict__ X, const float* __restrict__ CTX,
                            const unsigned short* __restrict__ WS,
                            const float* __restrict__ EB1,
                            const float* __restrict__ LNG, const float* __restrict__ LNB,
                            float* __restrict__ Z, unsigned short* __restrict__ SPP,
                            unsigned short* __restrict__ CIN, int l)
{
  __shared__ float sz[29 * 36];
  const int b = blockIdx.x, tid = threadIdx.x;
  const int lane = tid & 63, w = tid >> 6;
  const int lr = lane & 15, lg = lane >> 4, kb = lg * 8;

  if (l == 0) {
    for (int t = tid; t < 29 * 36; t += 256) {
      int i = t / 36, c = t - i * 36;
      float v = 0.f;
      if (c < 6) v = X[b * 174 + i * 6 + c];
      else if (c < 22) v = CTX[b * 464 + i * 16 + (c - 6)];
      sz[t] = v;
      if (c < 32) Z[(b * 29 + i) * 32 + c] = v;
    }
  } else {
    for (int t = tid; t < 29 * 36; t += 256) {
      int i = t / 36, c = t - i * 36;
      sz[t] = (c < 32) ? Z[(b * 29 + i) * 32 + c] : 0.f;
    }
  }
  __syncthreads();

  {
    int rt = w >> 1;
    int rowc = min(16 * rt + lr, 28);
    float zr[8];
    *(float4*)&zr[0] = *(const float4*)&sz[rowc * 36 + kb];
    *(float4*)&zr[4] = *(const float4*)&sz[rowc * 36 + kb + 4];
    short8 af = pack8(zr);
    int ntb = 4 * (w & 1);
    const unsigned short* wp = WS + (l * 4096 + ntb * 512 + lane * 8);
    #pragma unroll
    for (int t = 0; t < 4; ++t) {
      short8 bfr = *(const short8*)(wp + t * 512);
      f32x4 zz = {0.f, 0.f, 0.f, 0.f};
      f32x4 acc = __builtin_amdgcn_mfma_f32_16x16x32_bf16(af, bfr, zz, 0, 0, 0);
      int n = 16 * (ntb + t) + lr;
      float bias = (ntb + t < 4) ? LOG2E * EB1[l * 64 + n] : 0.f;
      #pragma unroll
      for (int r = 0; r < 4; ++r) {
        int orow = 16 * rt + 4 * lg + r;
        if (orow < 29) SPP[(b * 29 + orow) * 128 + n] = bf16b(acc[r] + bias);
      }
    }
  }
  if (w == 3 && lane < 29) {
    const float* row = &sz[lane * 36];
    float s = 0.f, q = 0.f;
    #pragma unroll
    for (int c4 = 0; c4 < 6; ++c4) {
      float4 v = *(const float4*)(row + 4 * c4);
      s += v.x + v.y + v.z + v.w;
      q += v.x * v.x + v.y * v.y + v.z * v.z + v.w * v.w;
    }
    float mu = s * (1.f / 22.f);
    float var = q * (1.f / 22.f) - mu * mu;
    float rr = rsqrtf(var + 1e-5f);
    unsigned short* crow = CIN + (b * 29 + lane) * 96;
    #pragma unroll
    for (int d = 0; d < 22; ++d)
      crow[d] = bf16b((row[d] - mu) * rr * LNG[l * 22 + d] + LNB[l * 22 + d]);
    #pragma unroll
    for (int d = 86; d < 96; ++d) crow[d] = 0;
  }
}

// ---- K2: edge phase (one wave per (b, i-quarter), no LDS). Scale-folded. ----
__launch_bounds__(256, 2)
__global__ void edge_kernel(const unsigned short* __restrict__ WS,
                            const unsigned short* __restrict__ SPP,
                            const float* __restrict__ EB2, const float* __restrict__ GW,
                            const float* __restrict__ GB,
                            unsigned short* __restrict__ CIN, int l)
{
  const int tid = threadIdx.x;
  const int lane = tid & 63, w = tid >> 6;
  const int lr = lane & 15, lg = lane >> 4, kb = lg * 8;
  const int wid = blockIdx.x * 4 + w;          // 4096 blocks -> 16384 waves
  const int b = wid >> 2;
  const int slot = wid & 3;
  const int i0 = (slot * 29) >> 2;
  const int i1 = ((slot + 1) * 29) >> 2;

  const unsigned short* wp = WS + (8192 + l * 4096 + lane * 8);
  short8 w2f[2][4];
  #pragma unroll
  for (int s = 0; s < 2; ++s)
    #pragma unroll
    for (int t = 0; t < 4; ++t)
      w2f[s][t] = *(const short8*)(wp + s * 2048 + t * 512);
  float eb2c[4], gwc[4];
  #pragma unroll
  for (int t = 0; t < 4; ++t) {
    eb2c[t] = LOG2E * EB2[l * 64 + 16 * t + lr];   // bias, pre-scaled: acc init
    gwc[t]  = GW [l * 64 + 16 * t + lr];           // unchanged (folds cancel)
  }
  const float gbv = LOG2E * GB[l];

  // pj panel cached in registers; rows 29..31 clamped (gated off)
  float pjf[2][2][8];
  #pragma unroll
  for (int tb = 0; tb < 2; ++tb) {
    int ja = min(tb * 16 + lr, 28);
    const unsigned short* pjrow = SPP + (b * 29 + ja) * 128 + 64 + kb;
    short8 p0 = *(const short8*)(pjrow);
    short8 p1 = *(const short8*)(pjrow + 32);
    #pragma unroll
    for (int m = 0; m < 8; ++m) { pjf[tb][0][m] = b2f(p0[m]); pjf[tb][1][m] = b2f(p1[m]); }
  }

  const unsigned short* pibase = SPP + b * 29 * 128 + kb;
  unsigned short* cbase = CIN + (b * 29) * 96 + 22 + lane;

  #pragma unroll 1
  for (int i = i0; i < i1; ++i) {
    short8 pb0 = *(const short8*)(pibase + i * 128);
    short8 pb1 = *(const short8*)(pibase + i * 128 + 32);
    float pif[2][8];
    #pragma unroll
    for (int m = 0; m < 8; ++m) { pif[0][m] = b2f(pb0[m]); pif[1][m] = b2f(pb1[m]); }

    float macc[4] = {0.f, 0.f, 0.f, 0.f};
    #pragma unroll
    for (int tb = 0; tb < 2; ++tb) {
      float m1[8];
      #pragma unroll
      for (int m = 0; m < 8; ++m) m1[m] = fsilu2(pif[0][m] + pjf[tb][0][m]);
      short8 af0 = pack8(m1);
      #pragma unroll
      for (int m = 0; m < 8; ++m) m1[m] = fsilu2(pif[1][m] + pjf[tb][1][m]);
      short8 af1 = pack8(m1);

      f32x4 a0 = {eb2c[0], eb2c[0], eb2c[0], eb2c[0]};
      f32x4 a1 = {eb2c[1], eb2c[1], eb2c[1], eb2c[1]};
      f32x4 a2 = {eb2c[2], eb2c[2], eb2c[2], eb2c[2]};
      f32x4 a3 = {eb2c[3], eb2c[3], eb2c[3], eb2c[3]};
      a0 = __builtin_amdgcn_mfma_f32_16x16x32_bf16(af0, w2f[0][0], a0, 0, 0, 0);
      a1 = __builtin_amdgcn_mfma_f32_16x16x32_bf16(af0, w2f[0][1], a1, 0, 0, 0);
      a2 = __builtin_amdgcn_mfma_f32_16x16x32_bf16(af0, w2f[0][2], a2, 0, 0, 0);
      a3 = __builtin_amdgcn_mfma_f32_16x16x32_bf16(af0, w2f[0][3], a3, 0, 0, 0);
      a0 = __builtin_amdgcn_mfma_f32_16x16x32_bf16(af1, w2f[1][0], a0, 0, 0, 0);
      a1 = __builtin_amdgcn_mfma_f32_16x16x32_bf16(af1, w2f[1][1], a1, 0, 0, 0);
      a2 = __builtin_amdgcn_mfma_f32_16x16x32_bf16(af1, w2f[1][2], a2, 0, 0, 0);
      a3 = __builtin_amdgcn_mfma_f32_16x16x32_bf16(af1, w2f[1][3], a3, 0, 0, 0);

      float m2v[4][4];
      #pragma unroll
      for (int r = 0; r < 4; ++r) {
        m2v[0][r] = fsilu2(a0[r]);
        m2v[1][r] = fsilu2(a1[r]);
        m2v[2][r] = fsilu2(a2[r]);
        m2v[3][r] = fsilu2(a3[r]);
      }
      float g0 = m2v[0][0]*gwc[0] + m2v[1][0]*gwc[1] + m2v[2][0]*gwc[2] + m2v[3][0]*gwc[3];
      float g1 = m2v[0][1]*gwc[0] + m2v[1][1]*gwc[1] + m2v[2][1]*gwc[2] + m2v[3][1]*gwc[3];
      float g2 = m2v[0][2]*gwc[0] + m2v[1][2]*gwc[1] + m2v[2][2]*gwc[2] + m2v[3][2]*gwc[3];
      float g3 = m2v[0][3]*gwc[0] + m2v[1][3]*gwc[1] + m2v[2][3]*gwc[2] + m2v[3][3]*gwc[3];
      g0 = row16_sum(g0); g1 = row16_sum(g1); g2 = row16_sum(g2); g3 = row16_sum(g3);
      float gg[4] = {g0, g1, g2, g3};
      #pragma unroll
      for (int r = 0; r < 4; ++r) {
        int jrow = tb * 16 + 4 * lg + r;
        float gv = (jrow < 29) ? fsigmoid2(gg[r] + gbv) : 0.f;
        macc[0] += m2v[0][r] * gv;
        macc[1] += m2v[1][r] * gv;
        macc[2] += m2v[2][r] * gv;
        macc[3] += m2v[3][r] * gv;
      }
    }

    float red0 = macc[0], red1 = macc[1], red2 = macc[2], red3 = macc[3];
    red0 += __shfl_xor(red0, 16, 64); red0 += __shfl_xor(red0, 32, 64);
    red1 += __shfl_xor(red1, 16, 64); red1 += __shfl_xor(red1, 32, 64);
    red2 += __shfl_xor(red2, 16, 64); red2 += __shfl_xor(red2, 32, 64);
    red3 += __shfl_xor(red3, 16, 64); red3 += __shfl_xor(red3, 32, 64);
    float vs = (lg == 0) ? red0 : (lg == 1) ? red1 : (lg == 2) ? red2 : red3;
    cbase[i * 96] = bf16b(vs);   // stores log2e * m_i; undone by NW1F fold
  }
}

// ---- K3: node MLP + residual (+ head when l==1) ----
__launch_bounds__(256, 4)
__global__ void node_kernel(const unsigned short* __restrict__ WS,
                            const unsigned short* __restrict__ CIN,
                            const float* __restrict__ NB1, const float* __restrict__ NB2,
                            float* __restrict__ Z,
                            const float* __restrict__ HW1, const float* __restrict__ HB1,
                            const float* __restrict__ HW2, const float* __restrict__ HB2,
                            float* __restrict__ OUTP, int l)
{
  __shared__ float sz[29 * 32];
  __shared__ float sh1[29 * 68];
  __shared__ float szm[22], shh[64], sob[24];
  const int b = blockIdx.x, tid = threadIdx.x;
  const int lane = tid & 63, w = tid >> 6;
  const int lr = lane & 15, lg = lane >> 4, kb = lg * 8;

  for (int t = tid; t < 29 * 8; t += 256)
    ((float4*)sz)[t] = ((const float4*)(Z + b * 29 * 32))[t];
  __syncthreads();

  // h1s = fsilu2(log2e*y1) = log2e*h1 -> sh1 ; NW2F carries the ln2 undo
  {
    int rt = w >> 1;
    int ntb = 2 * (w & 1);
    int rowc = min(16 * rt + lr, 28);
    const unsigned short* arow = CIN + (b * 29 + rowc) * 96 + kb;
    const unsigned short* wp = WS + (16384 + l * 6144 + ntb * 512 + lane * 8);
    f32x4 acc[2] = {{0.f,0.f,0.f,0.f}, {0.f,0.f,0.f,0.f}};
    #pragma unroll
    for (int s = 0; s < 3; ++s) {
      short8 af = *(const short8*)(arow + 32 * s);
      #pragma unroll
      for (int t = 0; t < 2; ++t) {
        short8 bfr = *(const short8*)(wp + s * 2048 + t * 512);
        acc[t] = __builtin_amdgcn_mfma_f32_16x16x32_bf16(af, bfr, acc[t], 0, 0, 0);
      }
    }
    #pragma unroll
    for (int t = 0; t < 2; ++t) {
      int n = 16 * (ntb + t) + lr;
      float bias = LOG2E * NB1[l * 64 + n];
      #pragma unroll
      for (int r = 0; r < 4; ++r) {
        int orow = 16 * rt + 4 * lg + r;
        if (orow < 29) sh1[orow * 68 + n] = fsilu2(acc[t][r] + bias);
      }
    }
  }
  __syncthreads();

  {
    int rt = w & 1;
    int nt = w >> 1;
    int rowc = min(16 * rt + lr, 28);
    int d = 16 * nt + lr;
    const unsigned short* wp = WS + (28672 + l * 2048 + nt * 512 + lane * 8);
    f32x4 acc = {0.f, 0.f, 0.f, 0.f};
    #pragma unroll
    for (int s = 0; s < 2; ++s) {
      float ar[8];
      *(float4*)&ar[0] = *(const float4*)&sh1[rowc * 68 + kb + 32 * s];
      *(float4*)&ar[4] = *(const float4*)&sh1[rowc * 68 + kb + 32 * s + 4];
      short8 af = pack8(ar);
      short8 bfr = *(const short8*)(wp + s * 1024);
      acc = __builtin_amdgcn_mfma_f32_16x16x32_bf16(af, bfr, acc, 0, 0, 0);
    }
    float bias = (d < 22) ? NB2[l * 22 + d] : 0.f;
    #pragma unroll
    for (int r = 0; r < 4; ++r) {
      int orow = 16 * rt + 4 * lg + r;
      if (orow < 29 && d < 22) sz[orow * 32 + d] += acc[r] + bias;
    }
  }
  __syncthreads();

  if (l == 0) {
    for (int t = tid; t < 29 * 8; t += 256)
      ((float4*)(Z + b * 29 * 32))[t] = ((const float4*)sz)[t];
  } else {
    if (tid < 22) {
      float s = 0.f;
      #pragma unroll
      for (int i = 0; i < 29; ++i) s += sz[i * 32 + tid];
      szm[tid] = s * (1.f / 29.f);
    }
    __syncthreads();
    if (tid < 64) {
      float a = HB1[tid];
      #pragma unroll
      for (int d = 0; d < 22; ++d) a += szm[d] * HW1[d * 64 + tid];
      shh[tid] = fmaxf(a, 0.f);
    }
    __syncthreads();
    if (tid < 24) {
      float a = HB2[tid];
      #pragma unroll
      for (int m = 0; m < 64; ++m) a += shh[m] * HW2[m * 24 + tid];
      sob[tid] = a;
    }
    __syncthreads();
    for (int t = tid; t < 29 * 12; t += 256)
      OUTP[b * 348 + t] = (t < 24) ? sob[t] : 0.f;
  }
}

extern "C" void kernel_launch(void* const* d_in, const int* in_sizes, int n_in,
                              void* d_out, int out_size, void* d_ws, size_t ws_size,
                              hipStream_t stream) {
  const float* X   = (const float*)d_in[0];
  const float* CTX = (const float*)d_in[1];
  const float* EW1 = (const float*)d_in[2];
  const float* EB1 = (const float*)d_in[3];
  const float* EW2 = (const float*)d_in[4];
  const float* EB2 = (const float*)d_in[5];
  const float* GW  = (const float*)d_in[6];
  const float* GB  = (const float*)d_in[7];
  const float* LNG = (const float*)d_in[8];
  const float* LNB = (const float*)d_in[9];
  const float* NW1 = (const float*)d_in[10];
  const float* NB1 = (const float*)d_in[11];
  const float* NW2 = (const float*)d_in[12];
  const float* NB2 = (const float*)d_in[13];
  const float* HW1 = (const float*)d_in[14];
  const float* HB1 = (const float*)d_in[15];
  const float* HW2 = (const float*)d_in[16];
  const float* HB2 = (const float*)d_in[17];
  float* OUTP = (float*)d_out;

  // workspace: WS fragments 64KB | Z f32 15.2MB | SPP bf16 30.4MB | CIN bf16 22.8MB
  unsigned short* WS = (unsigned short*)d_ws;
  float* Z = (float*)((char*)d_ws + 65536);
  unsigned short* SPP = (unsigned short*)((char*)d_ws + 65536 + 15204352);
  unsigned short* CIN = (unsigned short*)((char*)d_ws + 65536 + 15204352 + 30408704);

  hipLaunchKernelGGL(setup_kernel, dim3(128), dim3(256), 0, stream,
                     EW1, EW2, NW1, NW2, WS);
  for (int l = 0; l < 2; ++l) {
    hipLaunchKernelGGL(proj_kernel, dim3(4096), dim3(256), 0, stream,
                       X, CTX, WS, EB1, LNG, LNB, Z, SPP, CIN, l);
    hipLaunchKernelGGL(edge_kernel, dim3(4096), dim3(256), 0, stream,
                       WS, SPP, EB2, GW, GB, CIN, l);
    hipLaunchKernelGGL(node_kernel, dim3(4096), dim3(256), 0, stream,
                       WS, CIN, NB1, NB2, Z, HW1, HB1, HW2, HB2, OUTP, l);
  }
}